// Round 2
// baseline (723.967 us; speedup 1.0000x reference)
//
#include <hip/hip_runtime.h>
#include <hip/hip_bf16.h>
#include <hip/hip_cooperative_groups.h>
#include <math.h>

// ---------------------------------------------------------------------------
// Graft_StackedDense:
//   W0 = blend(w0, g0, p0)  [512,1024]   W1 = blend(w1, g1, p1)  [1,512]
//   out = relu(x @ W0^T + b0) @ W1^T + b1,  x:[65536,1024] fp32
//
// R3:
//  * main_mfma: true 2-phase pipeline — double-buffered As/Bs, tile t+1's
//    global_load_lds issued BEFORE tile t's MFMAs (loads fly under compute,
//    one barrier per K-step). W0b stored K-TILED ([k0/32][h][32]) so each
//    32KB B-tile is a dense flat copy (fully coalesced async16).
//  * all prepasses fused into ONE cooperative kernel (grid.sync between
//    phases); non-cooperative fallback retained.
// ---------------------------------------------------------------------------

typedef __attribute__((ext_vector_type(8))) short short8;
typedef __attribute__((ext_vector_type(4))) short short4v;
typedef __attribute__((ext_vector_type(4))) float floatx4;
typedef unsigned short ushort_t;

#define WS_ENT 0
#define WS_MM 4
#define WS_CNT 16
#define WS_W0B_WORD 64                    // bf16 W0b (K-tiled): 512*1024 ushorts
#define WS_W1B_WORD (64 + 262144)         // float W1b[512]

__device__ __forceinline__ unsigned f2ord(float f) {
    unsigned u = __float_as_uint(f);
    return (u & 0x80000000u) ? ~u : (u | 0x80000000u);
}
__device__ __forceinline__ float ord2f(unsigned k) {
    unsigned u = (k & 0x80000000u) ? (k ^ 0x80000000u) : ~k;
    return __uint_as_float(u);
}
__device__ __forceinline__ short f2bf(float f) {
    union { __hip_bfloat16 h; short s; } u;
    u.h = __float2bfloat16(f);
    return u.s;
}
__device__ __forceinline__ float blend_factor(float d, float wg) {
    float wl = 1.0f / (1.0f + expf(-d));
    float wb = wg * (1.0f - expf(-wg * wl));
    float wgr = (1.0f - wg) * (1.0f - expf(-(1.0f - wg) * (1.0f - wl)));
    return 1.0f / (1.0f + expf(-(wb - wgr)));
}
__device__ __forceinline__ float wglobal_from_ent(float eb, float eg) {
    return 0.12732395447351627f * atanf(500.0f * (eb - eg)) + 0.5f;
}
__device__ __forceinline__ void async16(const void* g, void* s) {
    __builtin_amdgcn_global_load_lds(
        (const __attribute__((address_space(1))) unsigned int*)g,
        (__attribute__((address_space(3))) unsigned int*)s, 16, 0, 0);
}

// ---------------------------------------------------------------------------
// Prepass phases (shared by cooperative kernel and fallback kernels)
// ---------------------------------------------------------------------------
__device__ __forceinline__ void phase_init(int tid, unsigned* ws_u) {
    if (tid < 4) {
        ws_u[WS_MM + 2 * tid] = 0xFFFFFFFFu;
        ws_u[WS_MM + 2 * tid + 1] = 0u;
    }
    if (tid >= WS_CNT && tid < WS_CNT + 40) ws_u[tid] = 0u;
}

// blocks 0..127 -> w0 slice; 128..255 -> g0 slice; blocks 0/1 also w1/g1.
__device__ __forceinline__ void phase_minmax(int bx, int tid,
                                             const float* w0, const float* g0,
                                             const float* w1, const float* g1,
                                             unsigned* ws_u) {
    __shared__ float smn[4], smx[4];
    int wave = tid >> 6, lane = tid & 63;
    int a = bx >> 7;
    const float* arr = (a ? g0 : w0) + (size_t)(bx & 127) * 4096;
    float mn = INFINITY, mx = -INFINITY;
    const float4* p4 = (const float4*)arr;
#pragma unroll
    for (int j = 0; j < 4; j++) {
        float4 v = p4[tid + j * 256];
        mn = fminf(mn, fminf(fminf(v.x, v.y), fminf(v.z, v.w)));
        mx = fmaxf(mx, fmaxf(fmaxf(v.x, v.y), fmaxf(v.z, v.w)));
    }
#pragma unroll
    for (int off = 32; off > 0; off >>= 1) {
        mn = fminf(mn, __shfl_xor(mn, off));
        mx = fmaxf(mx, __shfl_xor(mx, off));
    }
    if (lane == 0) { smn[wave] = mn; smx[wave] = mx; }
    __syncthreads();
    if (tid == 0) {
        mn = fminf(fminf(smn[0], smn[1]), fminf(smn[2], smn[3]));
        mx = fmaxf(fmaxf(smx[0], smx[1]), fmaxf(smx[2], smx[3]));
        atomicMin(&ws_u[WS_MM + 2 * a], f2ord(mn));
        atomicMax(&ws_u[WS_MM + 2 * a + 1], f2ord(mx));
    }
    if (bx < 2 && tid < 64) {
        const float* arr2 = bx ? g1 : w1;
        int a2 = 2 + bx;
        float mn2 = INFINITY, mx2 = -INFINITY;
#pragma unroll
        for (int j = 0; j < 8; j++) {
            float v = arr2[tid + 64 * j];
            mn2 = fminf(mn2, v);
            mx2 = fmaxf(mx2, v);
        }
#pragma unroll
        for (int off = 32; off > 0; off >>= 1) {
            mn2 = fminf(mn2, __shfl_xor(mn2, off));
            mx2 = fmaxf(mx2, __shfl_xor(mx2, off));
        }
        if (tid == 0) {
            atomicMin(&ws_u[WS_MM + 2 * a2], f2ord(mn2));
            atomicMax(&ws_u[WS_MM + 2 * a2 + 1], f2ord(mx2));
        }
    }
}

__device__ __forceinline__ void phase_hist(int bx, int tid,
                                           const float* w0, const float* g0,
                                           const float* w1, const float* g1,
                                           unsigned* ws_u) {
    int lane = tid & 63;
    {
        int a = bx >> 7;
        const float* arr = (a ? g0 : w0) + (size_t)(bx & 127) * 4096;
        float lo = ord2f(ws_u[WS_MM + 2 * a]);
        float hi = ord2f(ws_u[WS_MM + 2 * a + 1]);
        float scale = __fdiv_rn(__fsub_rn(hi, lo), 10.0f);
        float lw[11];
#pragma unroll
        for (int j = 0; j < 11; j++)
            lw[j] = __fadd_rn(lo, __fmul_rn((float)j, scale));
        unsigned c[10];
#pragma unroll
        for (int b = 0; b < 10; b++) c[b] = 0u;
        const float4* p4 = (const float4*)arr;
#pragma unroll
        for (int j = 0; j < 4; j++) {
            float4 v4 = p4[tid + j * 256];
            float vv[4] = {v4.x, v4.y, v4.z, v4.w};
#pragma unroll
            for (int e = 0; e < 4; e++) {
                float v = vv[e];
#pragma unroll
                for (int b = 0; b < 10; b++)
                    c[b] += (v >= lw[b] && v < lw[b + 1]) ? 1u : 0u;
            }
        }
#pragma unroll
        for (int b = 0; b < 10; b++) {
#pragma unroll
            for (int off = 32; off > 0; off >>= 1) c[b] += __shfl_xor(c[b], off);
        }
        if (lane == 0) {
#pragma unroll
            for (int b = 0; b < 10; b++)
                if (c[b] > 0u) atomicAdd(&ws_u[WS_CNT + a * 10 + b], c[b]);
        }
    }
    if (bx < 2 && tid < 64) {
        int a2 = 2 + bx;
        const float* arr2 = bx ? g1 : w1;
        float lo = ord2f(ws_u[WS_MM + 2 * a2]);
        float hi = ord2f(ws_u[WS_MM + 2 * a2 + 1]);
        float scale = __fdiv_rn(__fsub_rn(hi, lo), 10.0f);
        float lw[11];
#pragma unroll
        for (int j = 0; j < 11; j++)
            lw[j] = __fadd_rn(lo, __fmul_rn((float)j, scale));
        unsigned c[10];
#pragma unroll
        for (int b = 0; b < 10; b++) c[b] = 0u;
#pragma unroll
        for (int j = 0; j < 8; j++) {
            float v = arr2[tid + 64 * j];
#pragma unroll
            for (int b = 0; b < 10; b++)
                c[b] += (v >= lw[b] && v < lw[b + 1]) ? 1u : 0u;
        }
#pragma unroll
        for (int b = 0; b < 10; b++) {
#pragma unroll
            for (int off = 32; off > 0; off >>= 1) c[b] += __shfl_xor(c[b], off);
        }
        if (tid == 0) {
#pragma unroll
            for (int b = 0; b < 10; b++)
                if (c[b] > 0u) atomicAdd(&ws_u[WS_CNT + a2 * 10 + b], c[b]);
        }
    }
}

__device__ __forceinline__ void phase_ent(int tid, unsigned* ws_u) {
    if (tid < 4) {
        float n = (tid < 2) ? 524288.0f : 512.0f;
        float ent = 0.0f;
        for (int i = 0; i < 10; i++) {
            float p = __fdiv_rn((float)ws_u[WS_CNT + tid * 10 + i], n);
            if (p > 0.0f) ent = __fsub_rn(ent, __fmul_rn(p, logf(p)));
        }
        ((float*)ws_u)[WS_ENT + tid] = ent;
    }
}

__device__ __forceinline__ void phase_blend1(int bx, int tid,
                                             const float* w1, const float* g1,
                                             const float* p1, const float* ws_f,
                                             float* W1b) {
    __shared__ float diff[512];
    for (int i = tid; i < 512; i += 256) diff[i] = fabsf(w1[i] - g1[i]);
    __syncthreads();
    int wave = tid >> 6, lane = tid & 63;
    int i = bx * 4 + wave;
    float acc = 0.0f;
#pragma unroll
    for (int j = 0; j < 8; j++) {
        int k = lane + 64 * j;
        acc += diff[k] * p1[i * 512 + k];
    }
#pragma unroll
    for (int off = 32; off > 0; off >>= 1) acc += __shfl_xor(acc, off);
    if (lane == 0) {
        float wg = wglobal_from_ent(ws_f[WS_ENT + 2], ws_f[WS_ENT + 3]);
        float s0 = blend_factor(acc, wg);
        W1b[i] = w1[i] * s0 + g1[i] * (1.0f - s0);
    }
}

// W0 blend via bf16 MFMA; output written K-TILED: W0t[(i>>5)*16384 + o*32 + (i&31)]
__device__ __forceinline__ void phase_blend0(int bx, int tid,
                                             const float* w0, const float* g0,
                                             const float* p0, const float* ws_f,
                                             ushort_t* W0t) {
    __shared__ ushort_t As[32 * 40];
    __shared__ ushort_t Ps[64 * 40];
    int w = tid >> 6, l = tid & 63;
    int bo = (bx >> 4) * 32;   // o
    int bi = (bx & 15) * 64;   // i
    int wo = w & 1, wi = w >> 1;
    int m_in = l & 15, kq = l >> 4;

    floatx4 acc[2];
    const floatx4 zero = {0.0f, 0.0f, 0.0f, 0.0f};
    acc[0] = zero; acc[1] = zero;

    int ar = tid >> 3, ac = (tid & 7) * 4;
    int pr = tid >> 2, pc = (tid & 3) * 8;
    const float* wbase = w0 + (size_t)(bo + ar) * 1024 + ac;
    const float* gbase = g0 + (size_t)(bo + ar) * 1024 + ac;
    const float* pbase = p0 + (size_t)(bi + pr) * 1024 + pc;
    ushort_t* awr = &As[ar * 40 + ac];
    ushort_t* pwr = &Ps[pr * 40 + pc];

#pragma unroll 1
    for (int k0 = 0; k0 < 1024; k0 += 32) {
        float4 vw = *(const float4*)(wbase + k0);
        float4 vg = *(const float4*)(gbase + k0);
        float4 q0 = *(const float4*)(pbase + k0);
        float4 q1 = *(const float4*)(pbase + k0 + 4);
        short4v a4;
        a4[0] = f2bf(fabsf(vw.x - vg.x));
        a4[1] = f2bf(fabsf(vw.y - vg.y));
        a4[2] = f2bf(fabsf(vw.z - vg.z));
        a4[3] = f2bf(fabsf(vw.w - vg.w));
        short8 p8;
        p8[0] = f2bf(q0.x); p8[1] = f2bf(q0.y); p8[2] = f2bf(q0.z); p8[3] = f2bf(q0.w);
        p8[4] = f2bf(q1.x); p8[5] = f2bf(q1.y); p8[6] = f2bf(q1.z); p8[7] = f2bf(q1.w);
        *(short4v*)awr = a4;
        *(short8*)pwr = p8;
        __syncthreads();
        short8 af = *(const short8*)&As[(wo * 16 + m_in) * 40 + kq * 8];
        short8 pf0 = *(const short8*)&Ps[(wi * 32 + m_in) * 40 + kq * 8];
        short8 pf1 = *(const short8*)&Ps[(wi * 32 + 16 + m_in) * 40 + kq * 8];
        acc[0] = __builtin_amdgcn_mfma_f32_16x16x32_bf16(af, pf0, acc[0], 0, 0, 0);
        acc[1] = __builtin_amdgcn_mfma_f32_16x16x32_bf16(af, pf1, acc[1], 0, 0, 0);
        __syncthreads();
    }
    float wg = wglobal_from_ent(ws_f[WS_ENT + 0], ws_f[WS_ENT + 1]);
#pragma unroll
    for (int tn = 0; tn < 2; tn++) {
#pragma unroll
        for (int reg = 0; reg < 4; reg++) {
            int o = bo + wo * 16 + kq * 4 + reg;
            int i = bi + wi * 32 + tn * 16 + m_in;
            float s0 = blend_factor(acc[tn][reg], wg);
            float v = w0[o * 1024 + i] * s0 + g0[o * 1024 + i] * (1.0f - s0);
            W0t[(size_t)(i >> 5) * 16384 + o * 32 + (i & 31)] = (ushort_t)f2bf(v);
        }
    }
}

// ---------------------------------------------------------------------------
// Fused cooperative prepass: 1 launch replaces 6.
// ---------------------------------------------------------------------------
__global__ __launch_bounds__(256) void prep_coop(const float* w0, const float* g0,
                                                 const float* w1, const float* g1,
                                                 const float* p0, const float* p1,
                                                 unsigned* ws_u, ushort_t* W0t,
                                                 float* W1b) {
    cooperative_groups::grid_group grid = cooperative_groups::this_grid();
    int bx = blockIdx.x, tid = threadIdx.x;
    if (bx == 0) phase_init(tid, ws_u);
    __threadfence();
    grid.sync();
    phase_minmax(bx, tid, w0, g0, w1, g1, ws_u);
    __threadfence();
    grid.sync();
    phase_hist(bx, tid, w0, g0, w1, g1, ws_u);
    __threadfence();
    grid.sync();
    if (bx == 0) phase_ent(tid, ws_u);
    __threadfence();
    grid.sync();
    if (bx < 128) phase_blend1(bx, tid, w1, g1, p1, (const float*)ws_u, W1b);
    phase_blend0(bx, tid, w0, g0, p0, (const float*)ws_u, W0t);
}

// Fallback (non-cooperative) wrappers
__global__ __launch_bounds__(256) void k_init(unsigned* ws_u) {
    phase_init(threadIdx.x, ws_u);
}
__global__ __launch_bounds__(256) void k_minmax(const float* __restrict__ w0,
                                                const float* __restrict__ g0,
                                                const float* __restrict__ w1,
                                                const float* __restrict__ g1,
                                                unsigned* ws_u) {
    phase_minmax(blockIdx.x, threadIdx.x, w0, g0, w1, g1, ws_u);
}
__global__ __launch_bounds__(256) void k_hist(const float* __restrict__ w0,
                                              const float* __restrict__ g0,
                                              const float* __restrict__ w1,
                                              const float* __restrict__ g1,
                                              unsigned* ws_u) {
    phase_hist(blockIdx.x, threadIdx.x, w0, g0, w1, g1, ws_u);
}
__global__ void k_ent(unsigned* ws_u) { phase_ent(threadIdx.x, ws_u); }
__global__ __launch_bounds__(256) void k_blend1(const float* __restrict__ w1,
                                                const float* __restrict__ g1,
                                                const float* __restrict__ p1,
                                                const float* __restrict__ ws_f,
                                                float* __restrict__ W1b) {
    phase_blend1(blockIdx.x, threadIdx.x, w1, g1, p1, ws_f, W1b);
}
__global__ __launch_bounds__(256) void k_blend0(const float* __restrict__ w0,
                                                const float* __restrict__ g0,
                                                const float* __restrict__ p0,
                                                const float* __restrict__ ws_f,
                                                ushort_t* __restrict__ W0t) {
    phase_blend0(blockIdx.x, threadIdx.x, w0, g0, p0, ws_f, W0t);
}

// ---------------------------------------------------------------------------
// Main MFMA kernel. Block = 64(M) x 512(N = all of H), BK=32, 256 threads.
// Double-buffered 2-phase pipeline: tile t+1's loads issued before tile t's
// MFMAs; one barrier per K-step. W0t is K-tiled so each 32KB B-tile is a
// dense flat copy (async16 fully coalesced: 1KB/wave/instr).
// ---------------------------------------------------------------------------
__global__ __launch_bounds__(256, 2) void main_mfma(const float* __restrict__ x,
                                                    const float* __restrict__ b0,
                                                    const ushort_t* __restrict__ W0t,
                                                    const float* __restrict__ W1b,
                                                    const float* __restrict__ b1,
                                                    float* __restrict__ out) {
    __shared__ ushort_t As[2][64 * 40];    // [row][k] bf16, row stride 40 (pad 8)
    __shared__ ushort_t Bs[2][512 * 32];   // [h][k] bf16, linear (global_load_lds)
    __shared__ float red[4][64];
    int tid = threadIdx.x;
    int w = tid >> 6, l = tid & 63;
    int row0 = blockIdx.x * 64;
    int m_in = l & 15, kq = l >> 4;

    floatx4 acc[4][8];
    const floatx4 zero = {0.0f, 0.0f, 0.0f, 0.0f};
#pragma unroll
    for (int tm = 0; tm < 4; tm++)
#pragma unroll
        for (int tn = 0; tn < 8; tn++) acc[tm][tn] = zero;

    // A staging: thread t -> row t>>2 (0..63), k-chunk (t&3)*8 (8 floats)
    int arow = tid >> 2, acol = (tid & 3) * 8;
    const float* xbase = x + (size_t)(row0 + arow) * 1024 + acol;
    int awr_off = arow * 40 + acol;
    // B staging: flat 32KB tile copy; per-lane src = W0t + t*16384 + r*2048 + tid*8
    const ushort_t* bsrc = W0t + (size_t)tid * 8;

    // ---- prologue: tile 0 ----
    float4 pv0 = *(const float4*)(xbase);
    float4 pv1 = *(const float4*)(xbase + 4);
#pragma unroll
    for (int r = 0; r < 8; r++)
        async16(bsrc + r * 2048, &Bs[0][r * 2048 + w * 512]);
    {
        short8 s0;
        s0[0] = f2bf(pv0.x); s0[1] = f2bf(pv0.y); s0[2] = f2bf(pv0.z); s0[3] = f2bf(pv0.w);
        s0[4] = f2bf(pv1.x); s0[5] = f2bf(pv1.y); s0[6] = f2bf(pv1.z); s0[7] = f2bf(pv1.w);
        *(short8*)&As[0][awr_off] = s0;
    }
    __syncthreads();   // tile 0 resident

#pragma unroll 1
    for (int t = 0; t < 32; ++t) {
        int cur = t & 1, nxt = cur ^ 1;
        float4 nv0, nv1;
        if (t < 31) {
            const float* xn = xbase + (t + 1) * 32;
            nv0 = *(const float4*)xn;                 // A loads first (counted wait)
            nv1 = *(const float4*)(xn + 4);
            const ushort_t* bt = bsrc + (t + 1) * 16384;
#pragma unroll
            for (int r = 0; r < 8; r++)
                async16(bt + r * 2048, &Bs[nxt][r * 2048 + w * 512]);
        }
        // compute tile t while t+1 streams in
        short8 af[4];
#pragma unroll
        for (int tm = 0; tm < 4; tm++)
            af[tm] = *(const short8*)&As[cur][(tm * 16 + m_in) * 40 + kq * 8];
#pragma unroll
        for (int tn = 0; tn < 8; tn++) {
            short8 bfr = *(const short8*)&Bs[cur][(w * 128 + tn * 16 + m_in) * 32 + kq * 8];
#pragma unroll
            for (int tm = 0; tm < 4; tm++)
                acc[tm][tn] = __builtin_amdgcn_mfma_f32_16x16x32_bf16(
                    af[tm], bfr, acc[tm][tn], 0, 0, 0);
        }
        if (t < 31) {
            short8 s0;
            s0[0] = f2bf(nv0.x); s0[1] = f2bf(nv0.y); s0[2] = f2bf(nv0.z); s0[3] = f2bf(nv0.w);
            s0[4] = f2bf(nv1.x); s0[5] = f2bf(nv1.y); s0[6] = f2bf(nv1.z); s0[7] = f2bf(nv1.w);
            *(short8*)&As[nxt][awr_off] = s0;
        }
        __syncthreads();   // drains vmcnt (B tile t+1) + lgkm (A writes)
    }

    // epilogue: rows = row0 + tm*16 + kq*4 + reg; cols h = w*128 + tn*16 + m_in
    float b0v[8], w1v[8];
#pragma unroll
    for (int tn = 0; tn < 8; tn++) {
        int h = w * 128 + tn * 16 + m_in;
        b0v[tn] = b0[h];
        w1v[tn] = W1b[h];
    }
#pragma unroll
    for (int tm = 0; tm < 4; tm++) {
#pragma unroll
        for (int reg = 0; reg < 4; reg++) {
            float s = 0.0f;
#pragma unroll
            for (int tn = 0; tn < 8; tn++) {
                float y = acc[tm][tn][reg] + b0v[tn];
                y = fmaxf(y, 0.0f);
                s += y * w1v[tn];
            }
            s += __shfl_xor(s, 1);
            s += __shfl_xor(s, 2);
            s += __shfl_xor(s, 4);
            s += __shfl_xor(s, 8);
            if (m_in == 0) red[w][tm * 16 + kq * 4 + reg] = s;
        }
    }
    __syncthreads();
    if (tid < 64)
        out[row0 + tid] = red[0][tid] + red[1][tid] + red[2][tid] + red[3][tid] + b1[0];
}

// ---------------------------------------------------------------------------
extern "C" void kernel_launch(void* const* d_in, const int* in_sizes, int n_in,
                              void* d_out, int out_size, void* d_ws, size_t ws_size,
                              hipStream_t stream) {
    const float* x = (const float*)d_in[0];
    const float* w0 = (const float*)d_in[1];
    const float* b0 = (const float*)d_in[2];
    const float* w1 = (const float*)d_in[3];
    const float* b1 = (const float*)d_in[4];
    const float* p0 = (const float*)d_in[5];
    const float* p1 = (const float*)d_in[6];
    const float* g0 = (const float*)d_in[7];
    const float* g1 = (const float*)d_in[8];
    float* out = (float*)d_out;
    unsigned* ws_u = (unsigned*)d_ws;
    float* ws_f = (float*)d_ws;
    ushort_t* W0t = (ushort_t*)(ws_u + WS_W0B_WORD);
    float* W1b = ws_f + WS_W1B_WORD;

    void* args[] = {(void*)&w0, (void*)&g0, (void*)&w1, (void*)&g1,
                    (void*)&p0, (void*)&p1, (void*)&ws_u, (void*)&W0t, (void*)&W1b};
    hipError_t ce = hipLaunchCooperativeKernel((const void*)prep_coop, dim3(256),
                                               dim3(256), args, 0, stream);
    if (ce != hipSuccess) {
        // fallback: classic multi-launch pipeline
        k_init<<<1, 256, 0, stream>>>(ws_u);
        k_minmax<<<256, 256, 0, stream>>>(w0, g0, w1, g1, ws_u);
        k_hist<<<256, 256, 0, stream>>>(w0, g0, w1, g1, ws_u);
        k_ent<<<1, 64, 0, stream>>>(ws_u);
        k_blend1<<<128, 256, 0, stream>>>(w1, g1, p1, ws_f, W1b);
        k_blend0<<<256, 256, 0, stream>>>(w0, g0, p0, ws_f, W0t);
    }
    main_mfma<<<1024, 256, 0, stream>>>(x, b0, W0t, W1b, b1, out);
}

// Round 3
// 530.217 us; speedup vs baseline: 1.3654x; 1.3654x over previous
//
#include <hip/hip_runtime.h>
#include <hip/hip_bf16.h>
#include <math.h>

// ---------------------------------------------------------------------------
// Graft_StackedDense:
//   W0 = blend(w0, g0, p0)  [512,1024]   W1 = blend(w1, g1, p1)  [1,512]
//   out = relu(x @ W0^T + b0) @ W1^T + b1,  x:[65536,1024] fp32
//
// R4:
//  * cooperative prepass DROPPED (grid.sync cost 315us). 3 plain launches:
//      k_mm    - per-block partial min/max (plain stores, no init kernel;
//                block 2 zeroes hist counters)
//      k_hist  - in-block partial reduce -> register-counter histogram
//      k_blend - entropies from counts (in-block) + blend1 + blend0 (MFMA),
//                W0t written K-TILED and XOR-SWIZZLED
//  * main_mfma: double-buffered 2-phase pipeline (unchanged) + swizzled
//    Bs fragment reads: W0t layout bakes byte ^= ((row>>1)&3)<<4 so the
//    linear global_load_lds copy lands bank-conflict-free for ds_read_b128.
// ---------------------------------------------------------------------------

typedef __attribute__((ext_vector_type(8))) short short8;
typedef __attribute__((ext_vector_type(4))) short short4v;
typedef __attribute__((ext_vector_type(4))) float floatx4;
typedef unsigned short ushort_t;

#define WS_CNT 16                      // 40 words: 4 arrays x 10 bins
#define WS_PART 64                     // 256 partial (mn,mx) float pairs
#define WS_PART2 576                   // w1,g1 (mn,mx) pairs
#define WS_W0T 1024                    // bf16 W0t (K-tiled+swizzled): 262144 ushorts
#define WS_W1B (WS_W0T + 262144)       // float W1b[512]

__device__ __forceinline__ short f2bf(float f) {
    union { __hip_bfloat16 h; short s; } u;
    u.h = __float2bfloat16(f);
    return u.s;
}
__device__ __forceinline__ float blend_factor(float d, float wg) {
    float wl = 1.0f / (1.0f + expf(-d));
    float wb = wg * (1.0f - expf(-wg * wl));
    float wgr = (1.0f - wg) * (1.0f - expf(-(1.0f - wg) * (1.0f - wl)));
    return 1.0f / (1.0f + expf(-(wb - wgr)));
}
__device__ __forceinline__ float wglobal_from_ent(float eb, float eg) {
    return 0.12732395447351627f * atanf(500.0f * (eb - eg)) + 0.5f;
}
__device__ __forceinline__ void async16(const void* g, void* s) {
    __builtin_amdgcn_global_load_lds(
        (const __attribute__((address_space(1))) unsigned int*)g,
        (__attribute__((address_space(3))) unsigned int*)s, 16, 0, 0);
}
// swizzled ushort index of element (h, k) inside one [512][32] K-tile
__device__ __forceinline__ int swz_idx(int h, int k) {
    int kq = (k >> 3) & 3;
    return h * 32 + (((kq ^ ((h >> 1) & 3))) << 3) + (k & 7);
}

// ---------------------------------------------------------------------------
// k_mm: 256 blocks. Blocks [0,128): w0 slices; [128,256): g0 slices.
// Partial (mn,mx) -> plain stores at WS_PART + bx*2. Blocks 0/1 also do
// w1/g1 whole-array minmax -> WS_PART2. Block 2 zeroes the 40 counters.
// ---------------------------------------------------------------------------
__global__ __launch_bounds__(256) void k_mm(const float* __restrict__ w0,
                                            const float* __restrict__ g0,
                                            const float* __restrict__ w1,
                                            const float* __restrict__ g1,
                                            unsigned* ws_u) {
    float* ws_f = (float*)ws_u;
    __shared__ float smn[4], smx[4];
    int bx = blockIdx.x, tid = threadIdx.x;
    int wave = tid >> 6, lane = tid & 63;
    int a = bx >> 7;
    const float* arr = (a ? g0 : w0) + (size_t)(bx & 127) * 4096;
    float mn = INFINITY, mx = -INFINITY;
    const float4* p4 = (const float4*)arr;
#pragma unroll
    for (int j = 0; j < 4; j++) {
        float4 v = p4[tid + j * 256];
        mn = fminf(mn, fminf(fminf(v.x, v.y), fminf(v.z, v.w)));
        mx = fmaxf(mx, fmaxf(fmaxf(v.x, v.y), fmaxf(v.z, v.w)));
    }
#pragma unroll
    for (int off = 32; off > 0; off >>= 1) {
        mn = fminf(mn, __shfl_xor(mn, off));
        mx = fmaxf(mx, __shfl_xor(mx, off));
    }
    if (lane == 0) { smn[wave] = mn; smx[wave] = mx; }
    __syncthreads();
    if (tid == 0) {
        mn = fminf(fminf(smn[0], smn[1]), fminf(smn[2], smn[3]));
        mx = fmaxf(fmaxf(smx[0], smx[1]), fmaxf(smx[2], smx[3]));
        ws_f[WS_PART + bx * 2] = mn;
        ws_f[WS_PART + bx * 2 + 1] = mx;
    }
    if (bx < 2 && tid < 64) {
        const float* arr2 = bx ? g1 : w1;
        float mn2 = INFINITY, mx2 = -INFINITY;
#pragma unroll
        for (int j = 0; j < 8; j++) {
            float v = arr2[tid + 64 * j];
            mn2 = fminf(mn2, v);
            mx2 = fmaxf(mx2, v);
        }
#pragma unroll
        for (int off = 32; off > 0; off >>= 1) {
            mn2 = fminf(mn2, __shfl_xor(mn2, off));
            mx2 = fmaxf(mx2, __shfl_xor(mx2, off));
        }
        if (tid == 0) {
            ws_f[WS_PART2 + bx * 2] = mn2;
            ws_f[WS_PART2 + bx * 2 + 1] = mx2;
        }
    }
    if (bx == 2 && tid < 40) ws_u[WS_CNT + tid] = 0u;
}

// ---------------------------------------------------------------------------
// k_hist: 256 blocks, same slice mapping. Reduces the 128 partial pairs of
// its array in-block, then register-counter histogram + one atomicAdd/wave.
// ---------------------------------------------------------------------------
__global__ __launch_bounds__(256) void k_hist(const float* __restrict__ w0,
                                              const float* __restrict__ g0,
                                              const float* __restrict__ w1,
                                              const float* __restrict__ g1,
                                              unsigned* ws_u) {
    float* ws_f = (float*)ws_u;
    __shared__ float smn2[2], smx2[2];
    int bx = blockIdx.x, tid = threadIdx.x;
    int wave = tid >> 6, lane = tid & 63;
    int a = bx >> 7;
    // reduce 128 partial pairs (threads 0..127 = waves 0,1)
    float mn = INFINITY, mx = -INFINITY;
    if (tid < 128) {
        mn = ws_f[WS_PART + a * 256 + tid * 2];
        mx = ws_f[WS_PART + a * 256 + tid * 2 + 1];
    }
#pragma unroll
    for (int off = 32; off > 0; off >>= 1) {
        mn = fminf(mn, __shfl_xor(mn, off));
        mx = fmaxf(mx, __shfl_xor(mx, off));
    }
    if (wave < 2 && lane == 0) { smn2[wave] = mn; smx2[wave] = mx; }
    __syncthreads();
    float lo = fminf(smn2[0], smn2[1]);
    float hi = fmaxf(smx2[0], smx2[1]);

    float scale = __fdiv_rn(__fsub_rn(hi, lo), 10.0f);
    float lw[11];
#pragma unroll
    for (int j = 0; j < 11; j++)
        lw[j] = __fadd_rn(lo, __fmul_rn((float)j, scale));
    unsigned c[10];
#pragma unroll
    for (int b = 0; b < 10; b++) c[b] = 0u;
    const float* arr = (a ? g0 : w0) + (size_t)(bx & 127) * 4096;
    const float4* p4 = (const float4*)arr;
#pragma unroll
    for (int j = 0; j < 4; j++) {
        float4 v4 = p4[tid + j * 256];
        float vv[4] = {v4.x, v4.y, v4.z, v4.w};
#pragma unroll
        for (int e = 0; e < 4; e++) {
            float v = vv[e];
#pragma unroll
            for (int b = 0; b < 10; b++)
                c[b] += (v >= lw[b] && v < lw[b + 1]) ? 1u : 0u;
        }
    }
#pragma unroll
    for (int b = 0; b < 10; b++) {
#pragma unroll
        for (int off = 32; off > 0; off >>= 1) c[b] += __shfl_xor(c[b], off);
    }
    if (lane == 0) {
#pragma unroll
        for (int b = 0; b < 10; b++)
            if (c[b] > 0u) atomicAdd(&ws_u[WS_CNT + a * 10 + b], c[b]);
    }
    // w1/g1 (blocks 0/1, one wave)
    if (bx < 2 && tid < 64) {
        int a2 = 2 + bx;
        const float* arr2 = bx ? g1 : w1;
        float lo2 = ws_f[WS_PART2 + bx * 2];
        float hi2 = ws_f[WS_PART2 + bx * 2 + 1];
        float sc2 = __fdiv_rn(__fsub_rn(hi2, lo2), 10.0f);
        float lw2[11];
#pragma unroll
        for (int j = 0; j < 11; j++)
            lw2[j] = __fadd_rn(lo2, __fmul_rn((float)j, sc2));
        unsigned c2[10];
#pragma unroll
        for (int b = 0; b < 10; b++) c2[b] = 0u;
#pragma unroll
        for (int j = 0; j < 8; j++) {
            float v = arr2[tid + 64 * j];
#pragma unroll
            for (int b = 0; b < 10; b++)
                c2[b] += (v >= lw2[b] && v < lw2[b + 1]) ? 1u : 0u;
        }
#pragma unroll
        for (int b = 0; b < 10; b++) {
#pragma unroll
            for (int off = 32; off > 0; off >>= 1) c2[b] += __shfl_xor(c2[b], off);
        }
        if (tid == 0) {
#pragma unroll
            for (int b = 0; b < 10; b++)
                if (c2[b] > 0u) atomicAdd(&ws_u[WS_CNT + a2 * 10 + b], c2[b]);
        }
    }
}

// ---------------------------------------------------------------------------
// k_blend: 256 blocks. Entropies from counts in-block; blocks 0..127 also
// blend W1; all blocks blend one 32(o) x 64(i) W0 tile via bf16 MFMA and
// write W0t K-tiled + swizzled.
// ---------------------------------------------------------------------------
__global__ __launch_bounds__(256) void k_blend(const float* __restrict__ w0,
                                               const float* __restrict__ g0,
                                               const float* __restrict__ w1,
                                               const float* __restrict__ g1,
                                               const float* __restrict__ p0,
                                               const float* __restrict__ p1,
                                               unsigned* ws_u) {
    float* ws_f = (float*)ws_u;
    ushort_t* W0t = (ushort_t*)(ws_u + WS_W0T);
    float* W1b = ws_f + WS_W1B;
    __shared__ float ent_s[4];
    __shared__ float diff[512];
    __shared__ ushort_t As[32 * 40];
    __shared__ ushort_t Ps[64 * 40];
    int bx = blockIdx.x, tid = threadIdx.x;
    int w = tid >> 6, l = tid & 63;

    if (tid < 4) {
        float n = (tid < 2) ? 524288.0f : 512.0f;
        float ent = 0.0f;
        for (int i = 0; i < 10; i++) {
            float p = __fdiv_rn((float)ws_u[WS_CNT + tid * 10 + i], n);
            if (p > 0.0f) ent = __fsub_rn(ent, __fmul_rn(p, logf(p)));
        }
        ent_s[tid] = ent;
    }
    __syncthreads();
    float wg0 = wglobal_from_ent(ent_s[0], ent_s[1]);
    float wg1 = wglobal_from_ent(ent_s[2], ent_s[3]);

    // ---- blend1 (blocks 0..127, rows bx*4 + wave) ----
    if (bx < 128) {
        for (int i = tid; i < 512; i += 256) diff[i] = fabsf(w1[i] - g1[i]);
        __syncthreads();
        int i = bx * 4 + w;
        float acc = 0.0f;
#pragma unroll
        for (int j = 0; j < 8; j++) {
            int k = l + 64 * j;
            acc += diff[k] * p1[i * 512 + k];
        }
#pragma unroll
        for (int off = 32; off > 0; off >>= 1) acc += __shfl_xor(acc, off);
        if (l == 0) {
            float s0 = blend_factor(acc, wg1);
            W1b[i] = w1[i] * s0 + g1[i] * (1.0f - s0);
        }
    }

    // ---- blend0 ----
    int bo = (bx >> 4) * 32;   // o
    int bi = (bx & 15) * 64;   // i
    int wo = w & 1, wi = w >> 1;
    int m_in = l & 15, kq = l >> 4;

    floatx4 acc2[2];
    const floatx4 zero = {0.0f, 0.0f, 0.0f, 0.0f};
    acc2[0] = zero; acc2[1] = zero;

    int ar = tid >> 3, ac = (tid & 7) * 4;
    int pr = tid >> 2, pc = (tid & 3) * 8;
    const float* wbase = w0 + (size_t)(bo + ar) * 1024 + ac;
    const float* gbase = g0 + (size_t)(bo + ar) * 1024 + ac;
    const float* pbase = p0 + (size_t)(bi + pr) * 1024 + pc;
    ushort_t* awr = &As[ar * 40 + ac];
    ushort_t* pwr = &Ps[pr * 40 + pc];

#pragma unroll 1
    for (int k0 = 0; k0 < 1024; k0 += 32) {
        float4 vw = *(const float4*)(wbase + k0);
        float4 vg = *(const float4*)(gbase + k0);
        float4 q0 = *(const float4*)(pbase + k0);
        float4 q1 = *(const float4*)(pbase + k0 + 4);
        short4v a4;
        a4[0] = f2bf(fabsf(vw.x - vg.x));
        a4[1] = f2bf(fabsf(vw.y - vg.y));
        a4[2] = f2bf(fabsf(vw.z - vg.z));
        a4[3] = f2bf(fabsf(vw.w - vg.w));
        short8 p8;
        p8[0] = f2bf(q0.x); p8[1] = f2bf(q0.y); p8[2] = f2bf(q0.z); p8[3] = f2bf(q0.w);
        p8[4] = f2bf(q1.x); p8[5] = f2bf(q1.y); p8[6] = f2bf(q1.z); p8[7] = f2bf(q1.w);
        __syncthreads();   // also covers blend1's diff usage on first iter
        *(short4v*)awr = a4;
        *(short8*)pwr = p8;
        __syncthreads();
        short8 af = *(const short8*)&As[(wo * 16 + m_in) * 40 + kq * 8];
        short8 pf0 = *(const short8*)&Ps[(wi * 32 + m_in) * 40 + kq * 8];
        short8 pf1 = *(const short8*)&Ps[(wi * 32 + 16 + m_in) * 40 + kq * 8];
        acc2[0] = __builtin_amdgcn_mfma_f32_16x16x32_bf16(af, pf0, acc2[0], 0, 0, 0);
        acc2[1] = __builtin_amdgcn_mfma_f32_16x16x32_bf16(af, pf1, acc2[1], 0, 0, 0);
    }
#pragma unroll
    for (int tn = 0; tn < 2; tn++) {
#pragma unroll
        for (int reg = 0; reg < 4; reg++) {
            int o = bo + wo * 16 + kq * 4 + reg;
            int i = bi + wi * 32 + tn * 16 + m_in;
            float s0 = blend_factor(acc2[tn][reg], wg0);
            float v = w0[o * 1024 + i] * s0 + g0[o * 1024 + i] * (1.0f - s0);
            W0t[(size_t)(i >> 5) * 16384 + swz_idx(o, i & 31)] = (ushort_t)f2bf(v);
        }
    }
}

// ---------------------------------------------------------------------------
// Main MFMA kernel. Block = 64(M) x 512(N = all of H), BK=32, 256 threads.
// Double-buffered 2-phase pipeline; W0t K-tiled+swizzled so the flat
// global_load_lds copy lands the XOR-swizzled layout; fragment reads apply
// the same XOR -> ds_read_b128 at 2 dwords/bank (minimum, conflict-free).
// ---------------------------------------------------------------------------
__global__ __launch_bounds__(256, 2) void main_mfma(const float* __restrict__ x,
                                                    const float* __restrict__ b0,
                                                    const ushort_t* __restrict__ W0t,
                                                    const float* __restrict__ W1b,
                                                    const float* __restrict__ b1,
                                                    float* __restrict__ out) {
    __shared__ ushort_t As[2][64 * 40];    // [row][k] bf16, row stride 40 (pad 8)
    __shared__ ushort_t Bs[2][512 * 32];   // [h][k] bf16 swizzled, linear copy
    __shared__ float red[4][64];
    int tid = threadIdx.x;
    int w = tid >> 6, l = tid & 63;
    int row0 = blockIdx.x * 64;
    int m_in = l & 15, kq = l >> 4;

    floatx4 acc[4][8];
    const floatx4 zero = {0.0f, 0.0f, 0.0f, 0.0f};
#pragma unroll
    for (int tm = 0; tm < 4; tm++)
#pragma unroll
        for (int tn = 0; tn < 8; tn++) acc[tm][tn] = zero;

    // A staging: thread t -> row t>>2 (0..63), k-chunk (t&3)*8 (8 floats)
    int arow = tid >> 2, acol = (tid & 3) * 8;
    const float* xbase = x + (size_t)(row0 + arow) * 1024 + acol;
    int awr_off = arow * 40 + acol;
    // B staging: flat 32KB tile copy (layout pre-swizzled in W0t)
    const ushort_t* bsrc = W0t + (size_t)tid * 8;
    // swizzled fragment k-offset (row bits 1..2 = m_in bits 1..2)
    int bko = ((kq ^ ((m_in >> 1) & 3)) << 3);

    // ---- prologue: tile 0 ----
    float4 pv0 = *(const float4*)(xbase);
    float4 pv1 = *(const float4*)(xbase + 4);
#pragma unroll
    for (int r = 0; r < 8; r++)
        async16(bsrc + r * 2048, &Bs[0][r * 2048 + w * 512]);
    {
        short8 s0;
        s0[0] = f2bf(pv0.x); s0[1] = f2bf(pv0.y); s0[2] = f2bf(pv0.z); s0[3] = f2bf(pv0.w);
        s0[4] = f2bf(pv1.x); s0[5] = f2bf(pv1.y); s0[6] = f2bf(pv1.z); s0[7] = f2bf(pv1.w);
        *(short8*)&As[0][awr_off] = s0;
    }
    __syncthreads();   // tile 0 resident

#pragma unroll 1
    for (int t = 0; t < 32; ++t) {
        int cur = t & 1, nxt = cur ^ 1;
        float4 nv0, nv1;
        if (t < 31) {
            const float* xn = xbase + (t + 1) * 32;
            nv0 = *(const float4*)xn;
            nv1 = *(const float4*)(xn + 4);
            const ushort_t* bt = bsrc + (t + 1) * 16384;
#pragma unroll
            for (int r = 0; r < 8; r++)
                async16(bt + r * 2048, &Bs[nxt][r * 2048 + w * 512]);
        }
        // compute tile t while t+1 streams in
        short8 af[4];
#pragma unroll
        for (int tm = 0; tm < 4; tm++)
            af[tm] = *(const short8*)&As[cur][(tm * 16 + m_in) * 40 + kq * 8];
#pragma unroll
        for (int tn = 0; tn < 8; tn++) {
            int row = w * 128 + tn * 16 + m_in;
            short8 bfr = *(const short8*)&Bs[cur][row * 32 + bko];
#pragma unroll
            for (int tm = 0; tm < 4; tm++)
                acc[tm][tn] = __builtin_amdgcn_mfma_f32_16x16x32_bf16(
                    af[tm], bfr, acc[tm][tn], 0, 0, 0);
        }
        if (t < 31) {
            short8 s0;
            s0[0] = f2bf(nv0.x); s0[1] = f2bf(nv0.y); s0[2] = f2bf(nv0.z); s0[3] = f2bf(nv0.w);
            s0[4] = f2bf(nv1.x); s0[5] = f2bf(nv1.y); s0[6] = f2bf(nv1.z); s0[7] = f2bf(nv1.w);
            *(short8*)&As[nxt][awr_off] = s0;
        }
        __syncthreads();   // drains vmcnt (B tile t+1) + lgkm (A writes)
    }

    // epilogue: rows = row0 + tm*16 + kq*4 + reg; cols h = w*128 + tn*16 + m_in
    float b0v[8], w1v[8];
#pragma unroll
    for (int tn = 0; tn < 8; tn++) {
        int h = w * 128 + tn * 16 + m_in;
        b0v[tn] = b0[h];
        w1v[tn] = W1b[h];
    }
#pragma unroll
    for (int tm = 0; tm < 4; tm++) {
#pragma unroll
        for (int reg = 0; reg < 4; reg++) {
            float s = 0.0f;
#pragma unroll
            for (int tn = 0; tn < 8; tn++) {
                float y = acc[tm][tn][reg] + b0v[tn];
                y = fmaxf(y, 0.0f);
                s += y * w1v[tn];
            }
            s += __shfl_xor(s, 1);
            s += __shfl_xor(s, 2);
            s += __shfl_xor(s, 4);
            s += __shfl_xor(s, 8);
            if (m_in == 0) red[w][tm * 16 + kq * 4 + reg] = s;
        }
    }
    __syncthreads();
    if (tid < 64)
        out[row0 + tid] = red[0][tid] + red[1][tid] + red[2][tid] + red[3][tid] + b1[0];
}

// ---------------------------------------------------------------------------
extern "C" void kernel_launch(void* const* d_in, const int* in_sizes, int n_in,
                              void* d_out, int out_size, void* d_ws, size_t ws_size,
                              hipStream_t stream) {
    const float* x = (const float*)d_in[0];
    const float* w0 = (const float*)d_in[1];
    const float* b0 = (const float*)d_in[2];
    const float* w1 = (const float*)d_in[3];
    const float* b1 = (const float*)d_in[4];
    const float* p0 = (const float*)d_in[5];
    const float* p1 = (const float*)d_in[6];
    const float* g0 = (const float*)d_in[7];
    const float* g1 = (const float*)d_in[8];
    float* out = (float*)d_out;
    unsigned* ws_u = (unsigned*)d_ws;
    float* ws_f = (float*)d_ws;
    ushort_t* W0t = (ushort_t*)(ws_u + WS_W0T);
    float* W1b = ws_f + WS_W1B;

    k_mm<<<256, 256, 0, stream>>>(w0, g0, w1, g1, ws_u);
    k_hist<<<256, 256, 0, stream>>>(w0, g0, w1, g1, ws_u);
    k_blend<<<256, 256, 0, stream>>>(w0, g0, w1, g1, p0, p1, ws_u);
    main_mfma<<<1024, 256, 0, stream>>>(x, b0, W0t, W1b, b1, out);
}